// Round 7
// baseline (295.427 us; speedup 1.0000x reference)
//
#include <hip/hip_runtime.h>
#include <cstdint>
#include <cmath>

#define BDIM 256

constexpr int Bsz = 32;
constexpr int Tt  = 512;
constexpr int Nn  = 1024;
constexpr int SEG = 16;    // T split into 16 segments of 32 for the scan
constexpr int SLEN = 32;
constexpr int SPLITS = 8;  // split-K
constexpr int NKT = (2 * Bsz * Tt / 32) / SPLITS;  // 128 ktiles per split
constexpr float A_PLUS  = 0.005f;
constexpr float A_MINUS = 0.00525f;
constexpr float A_TP    = 0.0001f;
constexpr float A_TM    = 0.0001f;

typedef __attribute__((ext_vector_type(8))) short short8;   // 8 bf16 = 4 VGPRs
typedef __attribute__((ext_vector_type(4))) float float4v;  // MFMA acc

__device__ __forceinline__ unsigned short f2bf(float f) {
  // round-to-nearest-even fp32 -> bf16 (values are finite)
  unsigned u = __float_as_uint(f);
  u += 0x7fffu + ((u >> 16) & 1u);
  return (unsigned short)(u >> 16);
}

// ---------------------------------------------------------------------------
// Phase 1: trace recurrences -> bf16 operands, segment-scan parallelized.
// (unchanged — ~94 us; see journal)
// ---------------------------------------------------------------------------
__global__ __launch_bounds__(BDIM) void trace_kernel(
    const float* __restrict__ pre, const float* __restrict__ post,
    unsigned short* __restrict__ Abuf, unsigned short* __restrict__ Bbuf,
    float d_plus, float d_x, float d_minus, float d_y)
{
  // blockIdx.x: [0, 2*32*64): nb (64) | b (32) | side (2)
  int nb   = blockIdx.x & 63;
  int b    = (blockIdx.x >> 6) & 31;
  int side = blockIdx.x >> 11;
  int tid  = threadIdx.x;
  int seg  = tid >> 4;                             // [0,16)
  int nl   = tid & 15;
  int n    = nb * 16 + nl;

  const float* sp = (side ? post : pre) + (size_t)b * Tt * Nn + n;
  float da = side ? d_minus : d_plus;
  float db = side ? d_y     : d_x;
  float c1 = side ? -A_MINUS : A_PLUS;
  float c2 = side ? -A_TM    : A_TP;
  unsigned short* dbuf = side ? Bbuf : Abuf;
  int sw = (n >> 1) & 3;                           // bank swizzle for this row
  int t0 = seg * SLEN;
  int Kc = Bsz * Tt;

  // --- Phase A: load segment spikes (kept in registers), local endpoints ---
  float s[SLEN];
#pragma unroll
  for (int j = 0; j < SLEN; ++j) s[j] = sp[(size_t)(t0 + j) * Nn];

  float l1 = 0.f, l2 = 0.f;
#pragma unroll
  for (int j = 0; j < SLEN; ++j) {
    l1 = l1 * da + s[j];                           // combined step: decay then add
    l2 = l2 * db + s[j];
  }

  // d^32 via 5 squarings
  float dL1 = da, dL2 = db;
#pragma unroll
  for (int q = 0; q < 5; ++q) { dL1 *= dL1; dL2 *= dL2; }

  // --- Exclusive scan over the 16 segments of each chain, via LDS ---
  __shared__ float lds1[SEG][16], lds2[SEG][16];
  lds1[seg][nl] = l1; lds2[seg][nl] = l2;
  __syncthreads();
  float tr1 = 0.f, tr2 = 0.f;                      // carry entering this segment
#pragma unroll
  for (int m = 0; m < SEG - 1; ++m) {
    if (m < seg) {
      tr1 = tr1 * dL1 + lds1[m][nl];
      tr2 = tr2 * dL2 + lds2[m][nl];
    }
  }

  // --- Phase B: replay segment from registers, emit operands (16/batch) ---
#pragma unroll
  for (int g2 = 0; g2 < SLEN / 16; ++g2) {
    short8 w0[2], w1[2];
#pragma unroll
    for (int j = 0; j < 16; ++j) {
      float sv = s[g2 * 16 + j];
      tr1 *= da; tr2 *= db;                        // decay first
      float tv = c1 * tr1 + c2 * (tr1 * tr2);      // trace factor (pre spike-add)
      unsigned short bs = f2bf(sv);
      unsigned short bt = f2bf(tv);
      unsigned short h0 = side ? bs : bt;          // half0: P / post
      unsigned short h1 = side ? bt : bs;          // half1: pre / -Y
      w0[j >> 3][j & 7] = (short)h0;
      w1[j >> 3][j & 7] = (short)h1;
      tr1 += sv; tr2 += sv;                        // then add spike
    }
    int k0 = t0 + g2 * 16;                         // local t (multiple of 16)
    int kl = b * Tt + k0;                          // global row
    int slotbase = (k0 >> 3) & 3;                  // first 16B slot in this ktile
    size_t d0 = ((size_t)((kl >> 5) * 8 + (n >> 7))) * 4096 + (size_t)(n & 127) * 32;
    size_t d1 = ((size_t)(((Kc + kl) >> 5) * 8 + (n >> 7))) * 4096 + (size_t)(n & 127) * 32;
#pragma unroll
    for (int i = 0; i < 2; ++i) {
      int slot = slotbase + i;
      *(short8*)(dbuf + d0 + ((slot ^ sw) * 8)) = w0[i];   // swizzle in address only
      *(short8*)(dbuf + d1 + ((slot ^ sw) * 8)) = w1[i];
    }
  }
}

// ---------------------------------------------------------------------------
// Phase 2: wu_partial[s] = A^T * B over this split's k-range.
// NO LDS, NO BARRIERS: the global operand layout is already MFMA-fragment-
// contiguous (trace_kernel wrote it that way), so each wave streams fragments
// global->VGPR (perfectly coalesced dwordx4: 16 rows x 64B lines fully
// consumed per instruction) through a depth-3 register prefetch ring and
// back-to-back MFMAs. Intra-block x2 fragment reuse is served by L1/L2.
// ---------------------------------------------------------------------------
__global__ __launch_bounds__(BDIM) void gemm_kernel(
    const unsigned short* __restrict__ Abuf, const unsigned short* __restrict__ Bbuf,
    float* __restrict__ partials)
{
  int tid = threadIdx.x;
  int pt = blockIdx.x & 7;
  int qt = blockIdx.x >> 3;
  int s  = blockIdx.y;

  float4v acc[4][4];
#pragma unroll
  for (int i = 0; i < 4; ++i)
#pragma unroll
    for (int j = 0; j < 4; ++j) acc[i][j] = (float4v){0.f, 0.f, 0.f, 0.f};

  int wid = tid >> 6, lane = tid & 63;
  int wr = wid >> 1, wc = wid & 1;
  int rA = wr * 64 + (lane & 15);
  int rB = wc * 64 + (lane & 15);
  // swizzled 16B-slot: lane wants k-group (lane>>4); stored slot is ^((row>>1)&3)
  int kg = (((lane >> 4) ^ ((lane >> 1) & 3)) * 8);

  // per-lane fragment base pointers (advance 8 blobs = 32768 elems per ktile)
  const unsigned short* ga = Abuf + ((size_t)(s * NKT) * 8 + pt) * 4096 + rA * 32 + kg;
  const unsigned short* gb = Bbuf + ((size_t)(s * NKT) * 8 + qt) * 4096 + rB * 32 + kg;

  short8 afr[3][4], bfr[3][4];   // depth-3 prefetch ring (96 VGPR)

#define LOADK(kt_, buf_) do {                                               \
    const unsigned short* a_ = ga + (size_t)(kt_) * 32768;                  \
    const unsigned short* b_ = gb + (size_t)(kt_) * 32768;                  \
    _Pragma("unroll")                                                       \
    for (int mi = 0; mi < 4; ++mi) afr[buf_][mi] = *(const short8*)(a_ + mi * 512); \
    _Pragma("unroll")                                                       \
    for (int ni = 0; ni < 4; ++ni) bfr[buf_][ni] = *(const short8*)(b_ + ni * 512); \
  } while (0)

#define MM(buf_) do {                                                       \
    _Pragma("unroll")                                                       \
    for (int mi = 0; mi < 4; ++mi)                                          \
      _Pragma("unroll")                                                     \
      for (int ni = 0; ni < 4; ++ni)                                        \
        acc[mi][ni] = __builtin_amdgcn_mfma_f32_16x16x32_bf16(              \
            afr[buf_][mi], bfr[buf_][ni], acc[mi][ni], 0, 0, 0);            \
  } while (0)

  LOADK(0, 0);
  LOADK(1, 1);
  // NKT = 128 = 3*42 + 2: 42 full groups, then drain 2 buffers
#pragma unroll 1
  for (int kt = 0; kt <= NKT - 5; kt += 3) {
    LOADK(kt + 2, 2);
    MM(0);
    LOADK(kt + 3, 0);
    MM(1);
    LOADK(kt + 4, 1);
    MM(2);
  }
  MM(0);   // ktile 126
  MM(1);   // ktile 127

  // C/D layout: col = lane&15, row = (lane>>4)*4 + reg.  Single chunk: plain store.
  float* po = partials + (size_t)s * Nn * Nn;
#pragma unroll
  for (int mi = 0; mi < 4; ++mi)
#pragma unroll
    for (int r = 0; r < 4; ++r) {
      int row = pt * 128 + wr * 64 + mi * 16 + (lane >> 4) * 4 + r;
#pragma unroll
      for (int ni = 0; ni < 4; ++ni) {
        int col = qt * 128 + wc * 64 + ni * 16 + (lane & 15);
        po[(size_t)row * Nn + col] = acc[mi][ni][r];
      }
    }
#undef LOADK
#undef MM
}

// ---------------------------------------------------------------------------
// Phase 3: reduce split-K partials (float4), apply 1/(B*T)
// ---------------------------------------------------------------------------
__global__ __launch_bounds__(BDIM) void reduce_kernel(
    const float4v* __restrict__ partials, float4v* __restrict__ out, int S, float scale)
{
  size_t i = (size_t)blockIdx.x * BDIM + threadIdx.x;
  float4v v = (float4v){0.f, 0.f, 0.f, 0.f};
  for (int s = 0; s < S; ++s) v += partials[(size_t)s * (Nn * Nn / 4) + i];
  out[i] = v * scale;
}

extern "C" void kernel_launch(void* const* d_in, const int* in_sizes, int n_in,
                              void* d_out, int out_size, void* d_ws, size_t ws_size,
                              hipStream_t stream)
{
  const float* pre  = (const float*)d_in[0];
  const float* post = (const float*)d_in[1];
  float4v* out = (float4v*)d_out;
  char* ws = (char*)d_ws;

  size_t sizeAB = (size_t)2 * Bsz * Tt * Nn * 2;   // one operand buffer = 64 MB

  float* partials = (float*)ws;
  unsigned short* Abuf = (unsigned short*)(ws + (size_t)SPLITS * Nn * Nn * 4);
  unsigned short* Bbuf = (unsigned short*)(ws + (size_t)SPLITS * Nn * Nn * 4 + sizeAB);

  float d_plus  = expf(-1.0f / 20.0f);
  float d_x     = expf(-1.0f / 101.0f);
  float d_minus = expf(-1.0f / 20.0f);
  float d_y     = expf(-1.0f / 114.0f);

  trace_kernel<<<2 * Bsz * Nn / 16, BDIM, 0, stream>>>(
      pre, post, Abuf, Bbuf, d_plus, d_x, d_minus, d_y);
  gemm_kernel<<<dim3(64, SPLITS), BDIM, 0, stream>>>(Abuf, Bbuf, partials);
  reduce_kernel<<<(Nn * Nn / 4) / BDIM, BDIM, 0, stream>>>(
      (const float4v*)partials, out, SPLITS, 1.0f / (float)(Bsz * Tt));
}

// Round 8
// 259.425 us; speedup vs baseline: 1.1388x; 1.1388x over previous
//
#include <hip/hip_runtime.h>
#include <cstdint>
#include <cmath>

#define BDIM 256

constexpr int Bsz = 32;
constexpr int Tt  = 512;
constexpr int Nn  = 1024;
constexpr int SEG = 16;    // T split into 16 segments of 32 for the scan
constexpr int SLEN = 32;
constexpr int SPLITS = 8;  // split-K
constexpr int NKT = (2 * Bsz * Tt / 32) / SPLITS;  // 128 ktiles per split
constexpr float A_PLUS  = 0.005f;
constexpr float A_MINUS = 0.00525f;
constexpr float A_TP    = 0.0001f;
constexpr float A_TM    = 0.0001f;

typedef __attribute__((ext_vector_type(8))) short short8;   // 8 bf16 = 4 VGPRs
typedef __attribute__((ext_vector_type(4))) float float4v;  // MFMA acc

__device__ __forceinline__ unsigned short f2bf(float f) {
  // round-to-nearest-even fp32 -> bf16 (values are finite)
  unsigned u = __float_as_uint(f);
  u += 0x7fffu + ((u >> 16) & 1u);
  return (unsigned short)(u >> 16);
}

// ---------------------------------------------------------------------------
// Phase 1: trace recurrences -> bf16 operands, segment-scan parallelized.
// (unchanged — ~94 us; see journal)
// ---------------------------------------------------------------------------
__global__ __launch_bounds__(BDIM) void trace_kernel(
    const float* __restrict__ pre, const float* __restrict__ post,
    unsigned short* __restrict__ Abuf, unsigned short* __restrict__ Bbuf,
    float d_plus, float d_x, float d_minus, float d_y)
{
  // blockIdx.x: [0, 2*32*64): nb (64) | b (32) | side (2)
  int nb   = blockIdx.x & 63;
  int b    = (blockIdx.x >> 6) & 31;
  int side = blockIdx.x >> 11;
  int tid  = threadIdx.x;
  int seg  = tid >> 4;                             // [0,16)
  int nl   = tid & 15;
  int n    = nb * 16 + nl;

  const float* sp = (side ? post : pre) + (size_t)b * Tt * Nn + n;
  float da = side ? d_minus : d_plus;
  float db = side ? d_y     : d_x;
  float c1 = side ? -A_MINUS : A_PLUS;
  float c2 = side ? -A_TM    : A_TP;
  unsigned short* dbuf = side ? Bbuf : Abuf;
  int sw = (n >> 1) & 3;                           // bank swizzle for this row
  int t0 = seg * SLEN;
  int Kc = Bsz * Tt;

  // --- Phase A: load segment spikes (kept in registers), local endpoints ---
  float s[SLEN];
#pragma unroll
  for (int j = 0; j < SLEN; ++j) s[j] = sp[(size_t)(t0 + j) * Nn];

  float l1 = 0.f, l2 = 0.f;
#pragma unroll
  for (int j = 0; j < SLEN; ++j) {
    l1 = l1 * da + s[j];                           // combined step: decay then add
    l2 = l2 * db + s[j];
  }

  // d^32 via 5 squarings
  float dL1 = da, dL2 = db;
#pragma unroll
  for (int q = 0; q < 5; ++q) { dL1 *= dL1; dL2 *= dL2; }

  // --- Exclusive scan over the 16 segments of each chain, via LDS ---
  __shared__ float lds1[SEG][16], lds2[SEG][16];
  lds1[seg][nl] = l1; lds2[seg][nl] = l2;
  __syncthreads();
  float tr1 = 0.f, tr2 = 0.f;                      // carry entering this segment
#pragma unroll
  for (int m = 0; m < SEG - 1; ++m) {
    if (m < seg) {
      tr1 = tr1 * dL1 + lds1[m][nl];
      tr2 = tr2 * dL2 + lds2[m][nl];
    }
  }

  // --- Phase B: replay segment from registers, emit operands (16/batch) ---
#pragma unroll
  for (int g2 = 0; g2 < SLEN / 16; ++g2) {
    short8 w0[2], w1[2];
#pragma unroll
    for (int j = 0; j < 16; ++j) {
      float sv = s[g2 * 16 + j];
      tr1 *= da; tr2 *= db;                        // decay first
      float tv = c1 * tr1 + c2 * (tr1 * tr2);      // trace factor (pre spike-add)
      unsigned short bs = f2bf(sv);
      unsigned short bt = f2bf(tv);
      unsigned short h0 = side ? bs : bt;          // half0: P / post
      unsigned short h1 = side ? bt : bs;          // half1: pre / -Y
      w0[j >> 3][j & 7] = (short)h0;
      w1[j >> 3][j & 7] = (short)h1;
      tr1 += sv; tr2 += sv;                        // then add spike
    }
    int k0 = t0 + g2 * 16;                         // local t (multiple of 16)
    int kl = b * Tt + k0;                          // global row
    int slotbase = (k0 >> 3) & 3;                  // first 16B slot in this ktile
    size_t d0 = ((size_t)((kl >> 5) * 8 + (n >> 7))) * 4096 + (size_t)(n & 127) * 32;
    size_t d1 = ((size_t)(((Kc + kl) >> 5) * 8 + (n >> 7))) * 4096 + (size_t)(n & 127) * 32;
#pragma unroll
    for (int i = 0; i < 2; ++i) {
      int slot = slotbase + i;
      *(short8*)(dbuf + d0 + ((slot ^ sw) * 8)) = w0[i];   // swizzle in address only
      *(short8*)(dbuf + d1 + ((slot ^ sw) * 8)) = w1[i];
    }
  }
}

// ---------------------------------------------------------------------------
// Phase 2: wu_partial[s] = A^T * B over this split's k-range.
// R6 structure (best measured): 3-stage LDS ring, loads in flight across a
// bare s_barrier, fine-grained s_waitcnt vmcnt (never a full drain).
// NEW: XCD-aware flat grid — s = blockIdx.x & 7, so under round-robin
// workgroup->XCD dispatch all 64 tile-blocks of one split share one XCD's L2
// (each operand blob reused 8x in-L2 instead of fetched per-XCD from HBM).
// Performance heuristic only; correctness independent of mapping.
// ---------------------------------------------------------------------------
#define GLL(gp, lp)                                                         \
  __builtin_amdgcn_global_load_lds(                                         \
      (const __attribute__((address_space(1))) unsigned int*)(gp),          \
      (__attribute__((address_space(3))) unsigned int*)(lp), 16, 0, 0)

// s_waitcnt imm (gfx9 encoding): lgkm[11:8]=0xF (no wait), exp[6:4]=0x7,
// vmcnt low4 in [3:0], hi2 in [15:14]=0
#define WAITCNT_VM8 0xF78
#define WAITCNT_VM4 0xF74
#define WAITCNT_VM0 0xF70

__global__ __launch_bounds__(BDIM) void gemm_kernel(
    const unsigned short* __restrict__ Abuf, const unsigned short* __restrict__ Bbuf,
    float* __restrict__ partials)
{
  __shared__ unsigned short smem[3 * 8192];  // ring of 3 x (A 8KB-elems | B)
  int tid  = threadIdx.x;
  int s    = blockIdx.x & 7;                 // low bits -> XCD id under round-robin
  int tile = blockIdx.x >> 3;                // [0,64)
  int pt   = tile & 7;
  int qt   = tile >> 3;

  float4v acc[4][4];
#pragma unroll
  for (int i = 0; i < 4; ++i)
#pragma unroll
    for (int j = 0; j < 4; ++j) acc[i][j] = (float4v){0.f, 0.f, 0.f, 0.f};

  int wid = tid >> 6, lane = tid & 63;
  int wr = wid >> 1, wc = wid & 1;
  int rA = wr * 64 + (lane & 15);
  int rB = wc * 64 + (lane & 15);
  // swizzled 16B-slot: lane wants k-group (lane>>4); stored slot is ^((row>>1)&3)
  int kg = (((lane >> 4) ^ ((lane >> 1) & 3)) * 8);

  const unsigned short* ga = Abuf + ((size_t)(s * NKT) * 8 + pt) * 4096 + tid * 8;
  const unsigned short* gb = Bbuf + ((size_t)(s * NKT) * 8 + qt) * 4096 + tid * 8;

  // issue the 4 staging loads for tile kt into ring slot kt%3
#define ISSUE(kt_) do {                                                     \
    unsigned short* sb_ = smem + ((kt_) % 3) * 8192;                        \
    const unsigned short* a_ = ga + (size_t)(kt_) * 8 * 4096;               \
    const unsigned short* b_ = gb + (size_t)(kt_) * 8 * 4096;               \
    GLL(a_,        sb_ + tid * 8);                                          \
    GLL(a_ + 2048, sb_ + 2048 + tid * 8);                                   \
    GLL(b_,        sb_ + 4096 + tid * 8);                                   \
    GLL(b_ + 2048, sb_ + 6144 + tid * 8);                                   \
  } while (0)

  ISSUE(0);
  ISSUE(1);

  for (int kt = 0; kt < NKT; ++kt) {
    if (kt + 2 < NKT) {
      ISSUE(kt + 2);
      __builtin_amdgcn_s_waitcnt(WAITCNT_VM8);   // tile kt landed; kt+1,kt+2 in flight
    } else if (kt + 2 == NKT) {
      __builtin_amdgcn_s_waitcnt(WAITCNT_VM4);   // tile kt landed; kt+1 in flight
    } else {
      __builtin_amdgcn_s_waitcnt(WAITCNT_VM0);   // last tile
    }
    __builtin_amdgcn_s_barrier();                // bare barrier — no vmcnt(0) drain

    const unsigned short* sb = smem + (kt % 3) * 8192;
    short8 af[4], bfv[4];
#pragma unroll
    for (int mi = 0; mi < 4; ++mi)
      af[mi] = *(const short8*)(sb + (rA + mi * 16) * 32 + kg);       // ds_read_b128
#pragma unroll
    for (int ni = 0; ni < 4; ++ni)
      bfv[ni] = *(const short8*)(sb + 4096 + (rB + ni * 16) * 32 + kg);
#pragma unroll
    for (int mi = 0; mi < 4; ++mi)
#pragma unroll
      for (int ni = 0; ni < 4; ++ni)
        acc[mi][ni] = __builtin_amdgcn_mfma_f32_16x16x32_bf16(af[mi], bfv[ni], acc[mi][ni], 0, 0, 0);
  }

  // C/D layout: col = lane&15, row = (lane>>4)*4 + reg.  Single chunk: plain store.
  float* po = partials + (size_t)s * Nn * Nn;
#pragma unroll
  for (int mi = 0; mi < 4; ++mi)
#pragma unroll
    for (int r = 0; r < 4; ++r) {
      int row = pt * 128 + wr * 64 + mi * 16 + (lane >> 4) * 4 + r;
#pragma unroll
      for (int ni = 0; ni < 4; ++ni) {
        int col = qt * 128 + wc * 64 + ni * 16 + (lane & 15);
        po[(size_t)row * Nn + col] = acc[mi][ni][r];
      }
    }
#undef ISSUE
}

// ---------------------------------------------------------------------------
// Phase 3: reduce split-K partials (float4), apply 1/(B*T)
// ---------------------------------------------------------------------------
__global__ __launch_bounds__(BDIM) void reduce_kernel(
    const float4v* __restrict__ partials, float4v* __restrict__ out, int S, float scale)
{
  size_t i = (size_t)blockIdx.x * BDIM + threadIdx.x;
  float4v v = (float4v){0.f, 0.f, 0.f, 0.f};
  for (int s = 0; s < S; ++s) v += partials[(size_t)s * (Nn * Nn / 4) + i];
  out[i] = v * scale;
}

extern "C" void kernel_launch(void* const* d_in, const int* in_sizes, int n_in,
                              void* d_out, int out_size, void* d_ws, size_t ws_size,
                              hipStream_t stream)
{
  const float* pre  = (const float*)d_in[0];
  const float* post = (const float*)d_in[1];
  float4v* out = (float4v*)d_out;
  char* ws = (char*)d_ws;

  size_t sizeAB = (size_t)2 * Bsz * Tt * Nn * 2;   // one operand buffer = 64 MB

  float* partials = (float*)ws;
  unsigned short* Abuf = (unsigned short*)(ws + (size_t)SPLITS * Nn * Nn * 4);
  unsigned short* Bbuf = (unsigned short*)(ws + (size_t)SPLITS * Nn * Nn * 4 + sizeAB);

  float d_plus  = expf(-1.0f / 20.0f);
  float d_x     = expf(-1.0f / 101.0f);
  float d_minus = expf(-1.0f / 20.0f);
  float d_y     = expf(-1.0f / 114.0f);

  trace_kernel<<<2 * Bsz * Nn / 16, BDIM, 0, stream>>>(
      pre, post, Abuf, Bbuf, d_plus, d_x, d_minus, d_y);
  gemm_kernel<<<64 * SPLITS, BDIM, 0, stream>>>(Abuf, Bbuf, partials);
  reduce_kernel<<<(Nn * Nn / 4) / BDIM, BDIM, 0, stream>>>(
      (const float4v*)partials, out, SPLITS, 1.0f / (float)(Bsz * Tt));
}